// Round 6
// baseline (252.925 us; speedup 1.0000x reference)
//
#include <hip/hip_runtime.h>
#include <math.h>

// ---------------------------------------------------------------------------
// YOLOv5-style loss, 3 layers, fp32.
// R6: revert R5's channel split (regressed: 4x cnt re-read + imbalance).
// R4's scan was latency-bound at 1.5 waves/SIMD (394 blocks, 80 serial
// strided loads/thread). Fix TLP instead: 1 cell per thread (dword loads),
// 4x the waves (~6/SIMD), cnt/winner read once per cell, exec-masked loads
// in the class loop fetch only hit lanes. Line-fetch set identical to R4.
// ---------------------------------------------------------------------------

#define EPS 1e-7f
#define BS 16
#define NA 3
#define NC 80

#define LOG2E 1.44269504088896340736f
#define LN2   0.69314718055994530942f

struct Layer {
    const float* pred;
    const int*   b;
    const int*   a;
    const int*   gj;
    const int*   gi;
    const int*   tcls;
    const float* tbox;
    const float* anc;
    unsigned int* winner;   // [48*g*g] cells, 0 = empty else entry_idx+1
    unsigned int* cnt;      // [48*g*g] entry multiplicity per cell
    float*        iou;      // [n] CIoU per entry
    int g;
    int n;
};

struct Args {
    Layer L[3];
    int cum0;   // blocks of layer 0
    int cum1;   // blocks of layers 0+1
};

__device__ __forceinline__ int pick_layer(const Args& A, int& lb) {
    int bid = blockIdx.x;
    if (bid < A.cum0) { lb = bid; return 0; }
    if (bid < A.cum1) { lb = bid - A.cum0; return 1; }
    lb = bid - A.cum1; return 2;
}

// reduce two independent sums across a 256-thread block
__device__ __forceinline__ void block_reduce256_2(float& a, float& b) {
    #pragma unroll
    for (int o = 32; o > 0; o >>= 1) {
        a += __shfl_down(a, o, 64);
        b += __shfl_down(b, o, 64);
    }
    __shared__ float sma[4], smb[4];
    int lane = threadIdx.x & 63;
    int wid  = threadIdx.x >> 6;
    if (lane == 0) { sma[wid] = a; smb[wid] = b; }
    __syncthreads();
    if (threadIdx.x == 0) {
        a = sma[0] + sma[1] + sma[2] + sma[3];
        b = smb[0] + smb[1] + smb[2] + smb[3];
    }
}

// bce_with_logits(x, 0) via HW transcendentals: branchless, ~7 VALU ops
__device__ __forceinline__ float bce0(float x) {
    float t = __builtin_amdgcn_exp2f(-fabsf(x) * LOG2E);   // exp(-|x|)
    return fmaxf(x, 0.f) + LN2 * __builtin_amdgcn_logf(1.f + t);
}

// sigmoid via HW exp2 + rcp
__device__ __forceinline__ float fsigmoid(float x) {
    float e = __builtin_amdgcn_exp2f(-x * LOG2E);
    return __builtin_amdgcn_rcpf(1.f + e);
}

// --- kernel 1: per-entry CIoU + box loss + winner/cnt scatter + tcls gather -
__global__ void entry_kernel(Args A, float* acc) {
    int lb; int layer = pick_layer(A, lb);
    const Layer L = A.L[layer];
    int j = lb * 256 + (int)threadIdx.x;
    float box_c = 0.f;
    float neg_c = 0.f;    // x[tcls] to subtract from cls sum
    if (j < L.n) {
        int b  = L.b[j],  a  = L.a[j];
        int gy = L.gj[j], gx = L.gi[j];
        int g = L.g, gg = g * g;
        int q = b * NA + a;
        const float* base = L.pred + ((size_t)(q * 85) * gg + (size_t)gy * g + gx);
        float px = base[0];
        float py = base[gg];
        float pw = base[2 * (size_t)gg];
        float ph = base[3 * (size_t)gg];
        // decode
        float cx = 2.f * fsigmoid(px) - 0.5f;
        float cy = 2.f * fsigmoid(py) - 0.5f;
        float sw = 2.f * fsigmoid(pw);
        float sh = 2.f * fsigmoid(ph);
        float bw = sw * sw * L.anc[2 * j];
        float bh = sh * sh * L.anc[2 * j + 1];
        float fg = (float)g;
        float tx = L.tbox[4 * j + 0] * fg - (float)gx;
        float ty = L.tbox[4 * j + 1] * fg - (float)gy;
        float tw = L.tbox[4 * j + 2] * fg;
        float th = L.tbox[4 * j + 3] * fg;
        // CIoU
        float b1x1 = cx - bw * 0.5f, b1x2 = cx + bw * 0.5f;
        float b1y1 = cy - bh * 0.5f, b1y2 = cy + bh * 0.5f;
        float b2x1 = tx - tw * 0.5f, b2x2 = tx + tw * 0.5f;
        float b2y1 = ty - th * 0.5f, b2y2 = ty + th * 0.5f;
        float iw = fminf(b1x2, b2x2) - fmaxf(b1x1, b2x1);
        float ih = fminf(b1y2, b2y2) - fmaxf(b1y1, b2y1);
        float inter = fmaxf(iw, 0.f) * fmaxf(ih, 0.f);
        float w1 = b1x2 - b1x1, h1 = b1y2 - b1y1 + EPS;
        float w2 = b2x2 - b2x1, h2 = b2y2 - b2y1 + EPS;
        float uni = w1 * h1 + w2 * h2 - inter + EPS;
        float iou = inter / uni;
        float cw  = fmaxf(b1x2, b2x2) - fminf(b1x1, b2x1);
        float chh = fmaxf(b1y2, b2y2) - fminf(b1y1, b2y1);
        float c2  = cw * cw + chh * chh + EPS;
        float dx = b2x1 + b2x2 - b1x1 - b1x2;
        float dy = b2y1 + b2y2 - b1y1 - b1y2;
        float rho2 = (dx * dx + dy * dy) * 0.25f;
        float dv = atanf(w2 / h2) - atanf(w1 / h1);
        float v = (4.f / (float)(M_PI * M_PI)) * dv * dv;
        float alpha = v / (v - iou + (1.f + EPS));
        float ciou = iou - (rho2 / c2 + v * alpha);
        L.iou[j] = ciou;
        int cell = q * gg + gy * g + gx;
        atomicMax(&L.winner[cell], (unsigned int)(j + 1));
        atomicAdd(&L.cnt[cell], 1u);
        box_c = 1.f - ciou;
        // class positive term: bce(x,1) = bce(x,0) - x  -> subtract x[tcls]
        neg_c = base[(size_t)(5 + L.tcls[j]) * gg];
    }
    block_reduce256_2(box_c, neg_c);
    if (threadIdx.x == 0) {
        atomicAdd(&acc[0 + layer], box_c);
        atomicAdd(&acc[6 + layer], -neg_c);
    }
}

// --- kernel 2: per-cell channel-loop scan -----------------------------------
// One cell per thread: cnt/winner/obj loaded once (coalesced dwords), then
// the 80 class planes walked at stride gg with exec-masked loads (only
// lanes whose cell has entries fetch). 256 cells per block -> 4x the waves
// of the 4-cell version for latency hiding.
__global__ void scan_kernel(Args A, float* acc) {
    int lb; int layer = pick_layer(A, lb);
    const Layer L = A.L[layer];
    int gg = L.g * L.g;
    int cells = BS * NA * gg;
    int ci = lb * 256 + (int)threadIdx.x;
    float obj_s = 0.f, cls_s = 0.f;
    if (ci < cells) {
        int q = ci / gg;
        int e = ci - q * gg;
        unsigned c = L.cnt[ci];
        unsigned w = L.winner[ci];
        const float* pbase = L.pred + (size_t)(q * 85 + 4) * gg + e;
        float x = pbase[0];                           // objectness logit
        obj_s = bce0(x);
        if (w) obj_s -= x * fmaxf(L.iou[w - 1], 0.f);
        if (c) {
            float f = (float)c;
            const float* p = pbase + gg;
            #pragma unroll 16
            for (int r = 0; r < NC; ++r) {
                cls_s += f * bce0(p[(size_t)r * gg]);
            }
        }
    }
    block_reduce256_2(obj_s, cls_s);
    if (threadIdx.x == 0) {
        if (obj_s != 0.f) atomicAdd(&acc[3 + layer], obj_s);
        if (cls_s != 0.f) atomicAdd(&acc[6 + layer], cls_s);
    }
}

// --- kernel 3: combine ------------------------------------------------------
__global__ void final_kernel(const float* acc, float* out,
                             int n0, int n1, int n2,
                             int c0, int c1, int c2) {
    float box_l = acc[0] / (float)n0 + acc[1] / (float)n1 + acc[2] / (float)n2;
    float obj_l = 0.4f * acc[3] / (float)c0
                + 1.0f * acc[4] / (float)c1
                + 4.0f * acc[5] / (float)c2;
    float cls_l = acc[6] / ((float)n0 * NC)
                + acc[7] / ((float)n1 * NC)
                + acc[8] / ((float)n2 * NC);
    out[0] = 0.05f * box_l + 1.0f * obj_l + 0.5f * cls_l;
}

extern "C" void kernel_launch(void* const* d_in, const int* in_sizes, int n_in,
                              void* d_out, int out_size, void* d_ws, size_t ws_size,
                              hipStream_t stream) {
    (void)n_in; (void)out_size; (void)ws_size;
    char* ws = (char*)d_ws;

    Args A;
    int n[3], g[3], cells[3];
    size_t off = 64;                       // bytes 0..63: 9 float accumulators
    size_t winner_off[3], cnt_off[3], iou_off[3];

    for (int i = 0; i < 3; ++i) {
        n[i] = in_sizes[8 * i + 1];
        int gg = in_sizes[8 * i] / (BS * 255);
        int gv = (int)(sqrt((double)gg) + 0.5);
        g[i] = gv;
        cells[i] = BS * NA * gv * gv;
        winner_off[i] = off; off += (size_t)cells[i] * 4;
        cnt_off[i]    = off; off += (size_t)cells[i] * 4;
    }
    size_t zero_bytes = off;               // accumulators + winner + cnt
    for (int i = 0; i < 3; ++i) { iou_off[i] = off; off += (size_t)n[i] * 4; }

    for (int i = 0; i < 3; ++i) {
        Layer& L = A.L[i];
        L.pred = (const float*)d_in[8 * i + 0];
        L.b    = (const int*)  d_in[8 * i + 1];
        L.a    = (const int*)  d_in[8 * i + 2];
        L.gj   = (const int*)  d_in[8 * i + 3];
        L.gi   = (const int*)  d_in[8 * i + 4];
        L.tbox = (const float*)d_in[8 * i + 5];
        L.tcls = (const int*)  d_in[8 * i + 6];
        L.anc  = (const float*)d_in[8 * i + 7];
        L.winner = (unsigned int*)(ws + winner_off[i]);
        L.cnt    = (unsigned int*)(ws + cnt_off[i]);
        L.iou    = (float*)(ws + iou_off[i]);
        L.g = g[i];
        L.n = n[i];
    }
    float* acc = (float*)ws;

    hipMemsetAsync(d_ws, 0, zero_bytes, stream);

    // entry kernel: CIoU + scatter winner/cnt + tcls gather
    {
        int b0 = (n[0] + 255) / 256, b1 = (n[1] + 255) / 256, b2 = (n[2] + 255) / 256;
        A.cum0 = b0; A.cum1 = b0 + b1;
        entry_kernel<<<b0 + b1 + b2, 256, 0, stream>>>(A, acc);
    }
    // scan kernel: 256 cells per block (1 cell/thread)
    {
        int b0 = (cells[0] + 255) / 256;
        int b1 = (cells[1] + 255) / 256;
        int b2 = (cells[2] + 255) / 256;
        A.cum0 = b0; A.cum1 = b0 + b1;
        scan_kernel<<<b0 + b1 + b2, 256, 0, stream>>>(A, acc);
    }
    final_kernel<<<1, 1, 0, stream>>>(acc, (float*)d_out,
                                      n[0], n[1], n[2],
                                      cells[0], cells[1], cells[2]);
}

// Round 7
// 227.419 us; speedup vs baseline: 1.1122x; 1.1122x over previous
//
#include <hip/hip_runtime.h>
#include <math.h>

// ---------------------------------------------------------------------------
// YOLOv5-style loss, 3 layers, fp32.
// R7: revert to R4 structure (best). R5/R6 falsified the TLP theory; R6's
// numbers (~320 cyc/load/SIMD, VGPR=36) show the compiler serialized the
// class loop (load->use->load->use, ~1.5 loads in flight). Fix ILP/MLP:
// manual two-phase batches — load 20 float4 into a register array, then
// consume — 4 serial vmcnt waits per wave instead of ~80.
// ---------------------------------------------------------------------------

#define EPS 1e-7f
#define BS 16
#define NA 3
#define NC 80
#define BATCH 20            // float4 loads in flight per batch (80 VGPRs)

#define LOG2E 1.44269504088896340736f
#define LN2   0.69314718055994530942f

struct Layer {
    const float* pred;
    const int*   b;
    const int*   a;
    const int*   gj;
    const int*   gi;
    const int*   tcls;
    const float* tbox;
    const float* anc;
    unsigned int* winner;   // [48*g*g] cells, 0 = empty else entry_idx+1
    unsigned int* cnt;      // [48*g*g] entry multiplicity per cell
    float*        iou;      // [n] CIoU per entry
    int g;
    int n;
};

struct Args {
    Layer L[3];
    int cum0;   // blocks of layer 0
    int cum1;   // blocks of layers 0+1
};

__device__ __forceinline__ int pick_layer(const Args& A, int& lb) {
    int bid = blockIdx.x;
    if (bid < A.cum0) { lb = bid; return 0; }
    if (bid < A.cum1) { lb = bid - A.cum0; return 1; }
    lb = bid - A.cum1; return 2;
}

// reduce two independent sums across a 256-thread block
__device__ __forceinline__ void block_reduce256_2(float& a, float& b) {
    #pragma unroll
    for (int o = 32; o > 0; o >>= 1) {
        a += __shfl_down(a, o, 64);
        b += __shfl_down(b, o, 64);
    }
    __shared__ float sma[4], smb[4];
    int lane = threadIdx.x & 63;
    int wid  = threadIdx.x >> 6;
    if (lane == 0) { sma[wid] = a; smb[wid] = b; }
    __syncthreads();
    if (threadIdx.x == 0) {
        a = sma[0] + sma[1] + sma[2] + sma[3];
        b = smb[0] + smb[1] + smb[2] + smb[3];
    }
}

// bce_with_logits(x, 0) via HW transcendentals: branchless, ~7 VALU ops
__device__ __forceinline__ float bce0(float x) {
    float t = __builtin_amdgcn_exp2f(-fabsf(x) * LOG2E);   // exp(-|x|)
    return fmaxf(x, 0.f) + LN2 * __builtin_amdgcn_logf(1.f + t);
}

// sigmoid via HW exp2 + rcp
__device__ __forceinline__ float fsigmoid(float x) {
    float e = __builtin_amdgcn_exp2f(-x * LOG2E);
    return __builtin_amdgcn_rcpf(1.f + e);
}

// --- kernel 1: per-entry CIoU + box loss + winner/cnt scatter + tcls gather -
__global__ void entry_kernel(Args A, float* acc) {
    int lb; int layer = pick_layer(A, lb);
    const Layer L = A.L[layer];
    int j = lb * 256 + (int)threadIdx.x;
    float box_c = 0.f;
    float neg_c = 0.f;    // x[tcls] to subtract from cls sum
    if (j < L.n) {
        int b  = L.b[j],  a  = L.a[j];
        int gy = L.gj[j], gx = L.gi[j];
        int g = L.g, gg = g * g;
        int q = b * NA + a;
        const float* base = L.pred + ((size_t)(q * 85) * gg + (size_t)gy * g + gx);
        float px = base[0];
        float py = base[gg];
        float pw = base[2 * (size_t)gg];
        float ph = base[3 * (size_t)gg];
        // decode
        float cx = 2.f * fsigmoid(px) - 0.5f;
        float cy = 2.f * fsigmoid(py) - 0.5f;
        float sw = 2.f * fsigmoid(pw);
        float sh = 2.f * fsigmoid(ph);
        float bw = sw * sw * L.anc[2 * j];
        float bh = sh * sh * L.anc[2 * j + 1];
        float fg = (float)g;
        float tx = L.tbox[4 * j + 0] * fg - (float)gx;
        float ty = L.tbox[4 * j + 1] * fg - (float)gy;
        float tw = L.tbox[4 * j + 2] * fg;
        float th = L.tbox[4 * j + 3] * fg;
        // CIoU
        float b1x1 = cx - bw * 0.5f, b1x2 = cx + bw * 0.5f;
        float b1y1 = cy - bh * 0.5f, b1y2 = cy + bh * 0.5f;
        float b2x1 = tx - tw * 0.5f, b2x2 = tx + tw * 0.5f;
        float b2y1 = ty - th * 0.5f, b2y2 = ty + th * 0.5f;
        float iw = fminf(b1x2, b2x2) - fmaxf(b1x1, b2x1);
        float ih = fminf(b1y2, b2y2) - fmaxf(b1y1, b2y1);
        float inter = fmaxf(iw, 0.f) * fmaxf(ih, 0.f);
        float w1 = b1x2 - b1x1, h1 = b1y2 - b1y1 + EPS;
        float w2 = b2x2 - b2x1, h2 = b2y2 - b2y1 + EPS;
        float uni = w1 * h1 + w2 * h2 - inter + EPS;
        float iou = inter / uni;
        float cw  = fmaxf(b1x2, b2x2) - fminf(b1x1, b2x1);
        float chh = fmaxf(b1y2, b2y2) - fminf(b1y1, b2y1);
        float c2  = cw * cw + chh * chh + EPS;
        float dx = b2x1 + b2x2 - b1x1 - b1x2;
        float dy = b2y1 + b2y2 - b1y1 - b1y2;
        float rho2 = (dx * dx + dy * dy) * 0.25f;
        float dv = atanf(w2 / h2) - atanf(w1 / h1);
        float v = (4.f / (float)(M_PI * M_PI)) * dv * dv;
        float alpha = v / (v - iou + (1.f + EPS));
        float ciou = iou - (rho2 / c2 + v * alpha);
        L.iou[j] = ciou;
        int cell = q * gg + gy * g + gx;
        atomicMax(&L.winner[cell], (unsigned int)(j + 1));
        atomicAdd(&L.cnt[cell], 1u);
        box_c = 1.f - ciou;
        // class positive term: bce(x,1) = bce(x,0) - x  -> subtract x[tcls]
        neg_c = base[(size_t)(5 + L.tcls[j]) * gg];
    }
    block_reduce256_2(box_c, neg_c);
    if (threadIdx.x == 0) {
        atomicAdd(&acc[0 + layer], box_c);
        atomicAdd(&acc[6 + layer], -neg_c);
    }
}

// --- kernel 2: channel-loop scan with forced MLP ----------------------------
// Thread owns 4 consecutive cells (float4 column), loads cnt/winner once,
// then walks channels 5..84 in 4 batches of 20: phase 1 issues 20
// independent float4 loads into a register array, phase 2 consumes them.
// All loads wave-contiguous 1KB. Block covers 1024 cells.
__global__ void scan_kernel(Args A, float* acc) {
    int lb; int layer = pick_layer(A, lb);
    const Layer L = A.L[layer];
    int gg = L.g * L.g;
    int cells = BS * NA * gg;
    int ci = lb * 1024 + (int)threadIdx.x * 4;
    float obj_s = 0.f, cls_s = 0.f;
    if (ci < cells) {
        int q = ci / gg;
        int e = ci - q * gg;
        uint4 c4 = *(const uint4*)(L.cnt + ci);
        uint4 w4 = *(const uint4*)(L.winner + ci);
        const float* pbase = L.pred + (size_t)(q * 85 + 4) * gg + e;
        float4 x4 = *(const float4*)pbase;           // objectness channel
        obj_s = bce0(x4.x) + bce0(x4.y) + bce0(x4.z) + bce0(x4.w);
        if (w4.x) obj_s -= x4.x * fmaxf(L.iou[w4.x - 1], 0.f);
        if (w4.y) obj_s -= x4.y * fmaxf(L.iou[w4.y - 1], 0.f);
        if (w4.z) obj_s -= x4.z * fmaxf(L.iou[w4.z - 1], 0.f);
        if (w4.w) obj_s -= x4.w * fmaxf(L.iou[w4.w - 1], 0.f);
        if (c4.x | c4.y | c4.z | c4.w) {
            float f0 = (float)c4.x, f1 = (float)c4.y;
            float f2 = (float)c4.z, f3 = (float)c4.w;
            const float* p = pbase + gg;
            #pragma unroll
            for (int batch = 0; batch < NC / BATCH; ++batch) {
                float4 buf[BATCH];
                // phase 1: 20 independent loads, no consumers in between
                #pragma unroll
                for (int k = 0; k < BATCH; ++k)
                    buf[k] = *(const float4*)(p + (size_t)(batch * BATCH + k) * gg);
                // phase 2: consume
                #pragma unroll
                for (int k = 0; k < BATCH; ++k)
                    cls_s += f0 * bce0(buf[k].x) + f1 * bce0(buf[k].y)
                           + f2 * bce0(buf[k].z) + f3 * bce0(buf[k].w);
            }
        }
    }
    block_reduce256_2(obj_s, cls_s);
    if (threadIdx.x == 0) {
        if (obj_s != 0.f) atomicAdd(&acc[3 + layer], obj_s);
        if (cls_s != 0.f) atomicAdd(&acc[6 + layer], cls_s);
    }
}

// --- kernel 3: combine ------------------------------------------------------
__global__ void final_kernel(const float* acc, float* out,
                             int n0, int n1, int n2,
                             int c0, int c1, int c2) {
    float box_l = acc[0] / (float)n0 + acc[1] / (float)n1 + acc[2] / (float)n2;
    float obj_l = 0.4f * acc[3] / (float)c0
                + 1.0f * acc[4] / (float)c1
                + 4.0f * acc[5] / (float)c2;
    float cls_l = acc[6] / ((float)n0 * NC)
                + acc[7] / ((float)n1 * NC)
                + acc[8] / ((float)n2 * NC);
    out[0] = 0.05f * box_l + 1.0f * obj_l + 0.5f * cls_l;
}

extern "C" void kernel_launch(void* const* d_in, const int* in_sizes, int n_in,
                              void* d_out, int out_size, void* d_ws, size_t ws_size,
                              hipStream_t stream) {
    (void)n_in; (void)out_size; (void)ws_size;
    char* ws = (char*)d_ws;

    Args A;
    int n[3], g[3], cells[3];
    size_t off = 64;                       // bytes 0..63: 9 float accumulators
    size_t winner_off[3], cnt_off[3], iou_off[3];

    for (int i = 0; i < 3; ++i) {
        n[i] = in_sizes[8 * i + 1];
        int gg = in_sizes[8 * i] / (BS * 255);
        int gv = (int)(sqrt((double)gg) + 0.5);
        g[i] = gv;
        cells[i] = BS * NA * gv * gv;
        winner_off[i] = off; off += (size_t)cells[i] * 4;
        cnt_off[i]    = off; off += (size_t)cells[i] * 4;
    }
    size_t zero_bytes = off;               // accumulators + winner + cnt
    for (int i = 0; i < 3; ++i) { iou_off[i] = off; off += (size_t)n[i] * 4; }

    for (int i = 0; i < 3; ++i) {
        Layer& L = A.L[i];
        L.pred = (const float*)d_in[8 * i + 0];
        L.b    = (const int*)  d_in[8 * i + 1];
        L.a    = (const int*)  d_in[8 * i + 2];
        L.gj   = (const int*)  d_in[8 * i + 3];
        L.gi   = (const int*)  d_in[8 * i + 4];
        L.tbox = (const float*)d_in[8 * i + 5];
        L.tcls = (const int*)  d_in[8 * i + 6];
        L.anc  = (const float*)d_in[8 * i + 7];
        L.winner = (unsigned int*)(ws + winner_off[i]);
        L.cnt    = (unsigned int*)(ws + cnt_off[i]);
        L.iou    = (float*)(ws + iou_off[i]);
        L.g = g[i];
        L.n = n[i];
    }
    float* acc = (float*)ws;

    hipMemsetAsync(d_ws, 0, zero_bytes, stream);

    // entry kernel: CIoU + scatter winner/cnt + tcls gather
    {
        int b0 = (n[0] + 255) / 256, b1 = (n[1] + 255) / 256, b2 = (n[2] + 255) / 256;
        A.cum0 = b0; A.cum1 = b0 + b1;
        entry_kernel<<<b0 + b1 + b2, 256, 0, stream>>>(A, acc);
    }
    // scan kernel: 1024 cells per block, batched channel loop inside
    {
        int b0 = (cells[0] + 1023) / 1024;
        int b1 = (cells[1] + 1023) / 1024;
        int b2 = (cells[2] + 1023) / 1024;
        A.cum0 = b0; A.cum1 = b0 + b1;
        scan_kernel<<<b0 + b1 + b2, 256, 0, stream>>>(A, acc);
    }
    final_kernel<<<1, 1, 0, stream>>>(acc, (float*)d_out,
                                      n[0], n[1], n[2],
                                      cells[0], cells[1], cells[2]);
}